// Round 3
// baseline (2258.611 us; speedup 1.0000x reference)
//
#include <hip/hip_runtime.h>

// ---------------------------------------------------------------------------
// TransformerLM forward on gfx950.
// L=6, D=1024, H=16, HD=64, F=4096, V=32000, S=1024, B=2, Mtok = B*S = 2048.
// Strategy: f32 weights pre-transposed to bf16 [N][K] in ws once per call;
// all matmuls via v_mfma_f32_16x16x32_bf16; residual stream in f32.
// R1: gemm_bt staging via global_load_lds (16B) with linear LDS + XOR-swizzled
//     source/read (T2 both-sides rule).  [verified: conflicts=0, 2235 us]
// R2: (a) bijective XCD-chunked block remap in gemm_bt, m-fastest, so blocks
//         sharing a B-panel run temporally adjacent on one XCD (T1);
//     (b) attn_k 2 waves/block sharing one 32-row q-tile (16+16), shared Vt.
// ---------------------------------------------------------------------------

typedef __attribute__((ext_vector_type(8))) short short8;   // 8 bf16 = 4 VGPRs
typedef __attribute__((ext_vector_type(4))) float f32x4;

__device__ inline unsigned short f2bf(float f) {
  unsigned u = __builtin_bit_cast(unsigned, f);
  u += 0x7fffu + ((u >> 16) & 1u);           // RNE
  return (unsigned short)(u >> 16);
}

// global -> LDS direct copy, 16B per lane. LDS dest is wave-uniform base +
// lane*16 (linear); global src is per-lane (pre-swizzled by caller).
__device__ inline void gload_lds16(const unsigned short* g, unsigned short* l) {
  __builtin_amdgcn_global_load_lds(
      (const __attribute__((address_space(1))) void*)g,
      (__attribute__((address_space(3))) void*)l, 16, 0, 0);
}

// ---------------------------------------------------------------------------
// Transpose f32 [K][N] -> bf16 [N][K]
// ---------------------------------------------------------------------------
__global__ __launch_bounds__(256) void transpose_k(
    const float* __restrict__ src, unsigned short* __restrict__ dst,
    int K, int N, size_t srcStride, size_t dstStride) {
  __shared__ __align__(16) float tile[32 * 33];
  src += (size_t)blockIdx.z * srcStride;
  dst += (size_t)blockIdx.z * dstStride;
  const int k0 = blockIdx.y * 32, n0 = blockIdx.x * 32;
  const int t = threadIdx.x;
  {
    int k = t >> 3, n4 = (t & 7) << 2;
    float4 v = *(const float4*)&src[(size_t)(k0 + k) * N + n0 + n4];
    tile[k * 33 + n4 + 0] = v.x; tile[k * 33 + n4 + 1] = v.y;
    tile[k * 33 + n4 + 2] = v.z; tile[k * 33 + n4 + 3] = v.w;
  }
  __syncthreads();
  {
    int n = t >> 3, k4 = (t & 7) << 2;
    ushort4 o;
    o.x = f2bf(tile[(k4 + 0) * 33 + n]);
    o.y = f2bf(tile[(k4 + 1) * 33 + n]);
    o.z = f2bf(tile[(k4 + 2) * 33 + n]);
    o.w = f2bf(tile[(k4 + 3) * 33 + n]);
    *(ushort4*)&dst[(size_t)(n0 + n) * K + k0 + k4] = o;
  }
}

// ---------------------------------------------------------------------------
// Embedding gather: x[m][d] = emb[ids[m]][d]   (f32)
// ---------------------------------------------------------------------------
__global__ __launch_bounds__(256) void embed_k(
    const int* __restrict__ ids, const float* __restrict__ emb,
    float* __restrict__ x) {
  const int m = blockIdx.x, t = threadIdx.x;
  const int id = ids[m];
  ((float4*)(x + (size_t)m * 1024))[t] = ((const float4*)(emb + (size_t)id * 1024))[t];
}

// ---------------------------------------------------------------------------
// Tiny gate MLPs: sigmoid(gelu(sig@W1+b1)@W2+b2) for ag/fg, all layers/batch.
// gout layout: [w(ag=0,fg=1)][l][b][1024]
// ---------------------------------------------------------------------------
__global__ __launch_bounds__(256) void gates_k(
    const float* __restrict__ sig,
    const float* __restrict__ aW1, const float* __restrict__ ab1,
    const float* __restrict__ aW2, const float* __restrict__ ab2,
    const float* __restrict__ fW1, const float* __restrict__ fb1,
    const float* __restrict__ fW2, const float* __restrict__ fb2,
    float* __restrict__ gout) {
  const int b = blockIdx.x, l = blockIdx.y, w = blockIdx.z;
  const float* W1 = (w ? fW1 : aW1) + l * 96;
  const float* B1 = (w ? fb1 : ab1) + l * 32;
  const float* W2 = (w ? fW2 : aW2) + (size_t)l * 32 * 1024;
  const float* B2 = (w ? fb2 : ab2) + l * 1024;
  __shared__ float h[32];
  const int t = threadIdx.x;
  if (t < 32) {
    float a = sig[b * 3] * W1[t] + sig[b * 3 + 1] * W1[32 + t] + sig[b * 3 + 2] * W1[64 + t] + B1[t];
    h[t] = 0.5f * a * (1.0f + erff(a * 0.70710678118654752f));
  }
  __syncthreads();
  #pragma unroll
  for (int i = 0; i < 4; i++) {
    int d = t + i * 256;
    float a = B2[d];
    #pragma unroll
    for (int j = 0; j < 32; j++) a += h[j] * W2[j * 1024 + d];
    gout[(((size_t)w * 6 + l) * 2 + b) * 1024 + d] = 1.0f / (1.0f + expf(-a));
  }
}

// ---------------------------------------------------------------------------
// LayerNorm row kernel: x f32 [rows][1024] -> bf16 out (g,b applied)
// ---------------------------------------------------------------------------
__global__ __launch_bounds__(256) void ln_k(
    const float* __restrict__ x, const float* __restrict__ gw,
    const float* __restrict__ bw, unsigned short* __restrict__ out) {
  const int row = blockIdx.x, t = threadIdx.x;
  const float4 v = ((const float4*)(x + (size_t)row * 1024))[t];
  float s  = v.x + v.y + v.z + v.w;
  float s2 = v.x * v.x + v.y * v.y + v.z * v.z + v.w * v.w;
  #pragma unroll
  for (int m_ = 1; m_ < 64; m_ <<= 1) {
    s  += __shfl_xor(s, m_, 64);
    s2 += __shfl_xor(s2, m_, 64);
  }
  __shared__ float red[8];
  const int wv = t >> 6;
  if ((t & 63) == 0) { red[wv] = s; red[4 + wv] = s2; }
  __syncthreads();
  s  = red[0] + red[1] + red[2] + red[3];
  s2 = red[4] + red[5] + red[6] + red[7];
  const float mean = s * (1.0f / 1024.0f);
  const float var  = s2 * (1.0f / 1024.0f) - mean * mean;
  const float rstd = rsqrtf(var + 1e-5f);
  const float4 gv = ((const float4*)gw)[t];
  const float4 bv = ((const float4*)bw)[t];
  ushort4 o;
  o.x = f2bf((v.x - mean) * rstd * gv.x + bv.x);
  o.y = f2bf((v.y - mean) * rstd * gv.y + bv.y);
  o.z = f2bf((v.z - mean) * rstd * gv.z + bv.z);
  o.w = f2bf((v.w - mean) * rstd * gv.w + bv.w);
  ((ushort4*)(out + (size_t)row * 1024))[t] = o;
}

// ---------------------------------------------------------------------------
// Generic GEMM: C[M][N] = A[M][K](bf16) @ Bt[N][K](bf16)^T  + epilogue
// epi: 0 plain->bf16, 1 qkv (z<2 rope ->bf16, z==2 plain), 2 gate*val + resid
//      3 gelu->bf16, 5 logits->f32
//
// LDS layout (linear rows, 64 bf16 = 128 B per row), XOR-swizzled:
//   element (row, k) at byte  row*128 + (((k>>3) ^ (row&7)) * 16) + (k&7)*2
// Staged via global_load_lds: LDS dest linear (base + lane*16); the SOURCE
// column is pre-swizzled per lane:  col16 = (lane&7) ^ (lane>>3).
//
// Block remap (R2): hw dispatch order round-robins XCDs; we map hw id ->
// logical (n-major, m-fastest) via the bijective chunked transform so each
// XCD owns a contiguous n-panel range and the gridDim.y m-blocks of a panel
// run temporally adjacent on one XCD -> B fetched ~once per panel.
// ---------------------------------------------------------------------------
struct GArgs {
  const unsigned short *A, *Bt0, *Bt1, *Bt2;
  const float *bias0, *bias1, *bias2;
  unsigned short *ob0, *ob1, *ob2;
  float* xio;
  const float *gate, *ropec, *ropes;
  int M, N, K, epi;
};

template <int MT>   // rows per block = MT*32 (MT=4 ->128, MT=2 ->64); cols = 128
__global__ __launch_bounds__(256) void gemm_bt(GArgs g) {
  constexpr int BM = MT * 32;
  __shared__ __align__(16) unsigned short As[BM * 64];
  __shared__ __align__(16) unsigned short Bs[128 * 64];
  const int z = blockIdx.z;
  const unsigned short* A  = g.A;
  const unsigned short* Bt = (z == 0) ? g.Bt0 : (z == 1 ? g.Bt1 : g.Bt2);
  unsigned short* obf      = (z == 0) ? g.ob0 : (z == 1 ? g.ob1 : g.ob2);
  const float* bias        = (z == 0) ? g.bias0 : (z == 1 ? g.bias1 : g.bias2);

  // ---- XCD-aware bijective remap (per z-slice; gx*gy % 8 == 0 for all uses)
  const int nwg  = gridDim.x * gridDim.y;
  const int hwid = blockIdx.y * gridDim.x + blockIdx.x;
  const int xcd = hwid & 7, j8 = hwid >> 3;
  const int q8 = nwg >> 3, r8 = nwg & 7;
  const int logical =
      (xcd < r8 ? xcd * (q8 + 1) : r8 * (q8 + 1) + (xcd - r8) * q8) + j8;
  const int mIdx = logical % gridDim.y;      // m fastest -> B-panel reuse
  const int nIdx = logical / gridDim.y;
  const int m0 = mIdx * BM, n0 = nIdx * 128;

  const int t = threadIdx.x;
  const int wave = t >> 6, lane = t & 63, l16 = lane & 15, quad = lane >> 4;
  const int wm = wave >> 1, wn = wave & 1;
  const int K_ = g.K;

  // staging constants: each global_load_lds covers 8 rows x 64 bf16 (1 KiB).
  const int srow = lane >> 3;                 // row within 8-row group
  const int scol = (lane & 7) ^ srow;         // pre-swizzled source col16

  const f32x4 vzero = {0.0f, 0.0f, 0.0f, 0.0f};
  f32x4 acc[MT][4];
  #pragma unroll
  for (int i = 0; i < MT; i++)
    #pragma unroll
    for (int j = 0; j < 4; j++) acc[i][j] = vzero;

  for (int k0 = 0; k0 < K_; k0 += 64) {
    __syncthreads();                          // prior tile reads done
    #pragma unroll
    for (int i = 0; i < MT; i++) {            // stage A: BM x 64 bf16
      const int r0 = (wave * MT + i) * 8;
      gload_lds16(&A[(size_t)(m0 + r0 + srow) * K_ + k0 + scol * 8], &As[r0 * 64]);
    }
    #pragma unroll
    for (int i = 0; i < 4; i++) {             // stage B: 128 x 64 bf16
      const int r0 = (wave * 4 + i) * 8;
      gload_lds16(&Bt[(size_t)(n0 + r0 + srow) * K_ + k0 + scol * 8], &Bs[r0 * 64]);
    }
    __syncthreads();                          // drains vmcnt -> tile visible
    #pragma unroll
    for (int kk = 0; kk < 2; kk++) {
      short8 af[MT], bfr[4];
      #pragma unroll
      for (int mt = 0; mt < MT; mt++) {
        const int ar = wm * (MT * 16) + mt * 16 + l16;
        af[mt] = *(const short8*)&As[ar * 64 + (((kk * 4 + quad) ^ (ar & 7)) << 3)];
      }
      #pragma unroll
      for (int nt = 0; nt < 4; nt++) {
        const int br = wn * 64 + nt * 16 + l16;
        bfr[nt] = *(const short8*)&Bs[br * 64 + (((kk * 4 + quad) ^ (br & 7)) << 3)];
      }
      #pragma unroll
      for (int mt = 0; mt < MT; mt++)
        #pragma unroll
        for (int nt = 0; nt < 4; nt++)
          acc[mt][nt] = __builtin_amdgcn_mfma_f32_16x16x32_bf16(af[mt], bfr[nt], acc[mt][nt], 0, 0, 0);
    }
  }

  // epilogue: element (m, n): m = mbase + mt*16 + r, n = nb + nt*16
  const int mbase = m0 + wm * (MT * 16) + quad * 4;
  const int nb = n0 + wn * 64 + l16;
  const size_t Nsz = (size_t)g.N;
  float bv4[4];
  #pragma unroll
  for (int nt = 0; nt < 4; nt++) bv4[nt] = bias[nb + nt * 16];

  if (g.epi == 1 && z < 2) {           // RoPE for q/k, heads are 64-wide
    #pragma unroll
    for (int mt = 0; mt < MT; mt++) {
      float vv[4][4];
      #pragma unroll
      for (int nt = 0; nt < 4; nt++)
        #pragma unroll
        for (int r = 0; r < 4; r++) vv[nt][r] = acc[mt][nt][r] + bv4[nt];
      #pragma unroll
      for (int nt = 0; nt < 4; nt++) {
        const int d = (nb + nt * 16) & 63;
        #pragma unroll
        for (int r = 0; r < 4; r++) {
          const int m = mbase + mt * 16 + r;
          const int s = m & 1023;
          const float c = g.ropec[s * 64 + d], sn = g.ropes[s * 64 + d];
          const float rot = (nt < 2) ? -vv[nt + 2][r] : vv[nt - 2][r];
          obf[(size_t)m * Nsz + nb + nt * 16] = f2bf(vv[nt][r] * c + rot * sn);
        }
      }
    }
  } else if (g.epi <= 1) {             // plain bf16 (+bias)
    #pragma unroll
    for (int mt = 0; mt < MT; mt++)
      #pragma unroll
      for (int nt = 0; nt < 4; nt++)
        #pragma unroll
        for (int r = 0; r < 4; r++)
          obf[(size_t)(mbase + mt * 16 + r) * Nsz + nb + nt * 16] = f2bf(acc[mt][nt][r] + bv4[nt]);
  } else if (g.epi == 2) {             // (v+bias)*gate added into residual f32
    const int bb = m0 >> 10;           // batch uniform per block (128 | 1024)
    float gt[4];
    #pragma unroll
    for (int nt = 0; nt < 4; nt++) gt[nt] = g.gate[bb * 1024 + nb + nt * 16];
    #pragma unroll
    for (int mt = 0; mt < MT; mt++)
      #pragma unroll
      for (int nt = 0; nt < 4; nt++)
        #pragma unroll
        for (int r = 0; r < 4; r++) {
          const size_t idx = (size_t)(mbase + mt * 16 + r) * Nsz + nb + nt * 16;
          g.xio[idx] += (acc[mt][nt][r] + bv4[nt]) * gt[nt];
        }
  } else if (g.epi == 3) {             // exact gelu -> bf16
    #pragma unroll
    for (int mt = 0; mt < MT; mt++)
      #pragma unroll
      for (int nt = 0; nt < 4; nt++)
        #pragma unroll
        for (int r = 0; r < 4; r++) {
          float vg = acc[mt][nt][r] + bv4[nt];
          vg = 0.5f * vg * (1.0f + erff(vg * 0.70710678118654752f));
          obf[(size_t)(mbase + mt * 16 + r) * Nsz + nb + nt * 16] = f2bf(vg);
        }
  } else {                             // 5: logits f32
    #pragma unroll
    for (int mt = 0; mt < MT; mt++)
      #pragma unroll
      for (int nt = 0; nt < 4; nt++)
        #pragma unroll
        for (int r = 0; r < 4; r++)
          g.xio[(size_t)(mbase + mt * 16 + r) * Nsz + nb + nt * 16] = acc[mt][nt][r] + bv4[nt];
  }
}

// ---------------------------------------------------------------------------
// Flash attention, causal. 2 waves/block, one 32-row q-tile split 16+16
// (wave w owns rows q0+16w .. q0+16w+15); both waves have identical KV trip
// count since q0 % 32 == 0. Shared Vt staging (128 threads); per-wave Pl.
// q,k,v,o: bf16 [B*S][1024] with head offset h*64. Grid (S/32, B*H).
// ---------------------------------------------------------------------------
__global__ __launch_bounds__(128) void attn_k(
    const unsigned short* __restrict__ q, const unsigned short* __restrict__ k,
    const unsigned short* __restrict__ v, unsigned short* __restrict__ o) {
  __shared__ __align__(16) unsigned short Pl[2 * 16 * 72];
  __shared__ __align__(16) unsigned short Vt[64 * 72];
  const int t = threadIdx.x;
  const int wave = t >> 6, lane = t & 63, l16 = lane & 15, quad = lane >> 4;
  const int bh = blockIdx.y, b = bh >> 4, h = bh & 15;
  const int q0 = blockIdx.x * 32;
  const int qw = q0 + wave * 16;             // this wave's 16 q-rows
  const size_t base = (size_t)b * 1024 * 1024 + h * 64;
  const unsigned short* qh = q + base;
  const unsigned short* kh = k + base;
  const unsigned short* vh = v + base;
  unsigned short* oh = o + base;
  unsigned short* Pw = Pl + wave * 16 * 72;

  const f32x4 vzero = {0.0f, 0.0f, 0.0f, 0.0f};
  short8 qf[2];
  #pragma unroll
  for (int kt = 0; kt < 2; kt++)
    qf[kt] = *(const short8*)&qh[(size_t)(qw + l16) * 1024 + kt * 32 + quad * 8];

  f32x4 oacc[4];
  float mrun[4], lrun[4];
  #pragma unroll
  for (int jt = 0; jt < 4; jt++) oacc[jt] = vzero;
  #pragma unroll
  for (int r = 0; r < 4; r++) { mrun[r] = -1e30f; lrun[r] = 0.0f; }

  const int tmax = (q0 + 31) >> 6;
  for (int tt = 0; tt <= tmax; tt++) {
    const int s0 = tt * 64;
    short8 kf[4][2];
    #pragma unroll
    for (int st = 0; st < 4; st++)
      #pragma unroll
      for (int kt = 0; kt < 2; kt++)
        kf[st][kt] = *(const short8*)&kh[(size_t)(s0 + st * 16 + l16) * 1024 + kt * 32 + quad * 8];

    __syncthreads();                       // protect LDS from previous iter
    {                                      // stage V transposed: Vt[d][s], 128 thr
      const int p = t & 31, c0 = t >> 5;   // row-pair p, col-group c0 in [0,4)
      #pragma unroll
      for (int i = 0; i < 2; i++) {
        const int d0 = (c0 + i * 4) * 8;
        uint4 va = *(const uint4*)&vh[(size_t)(s0 + 2 * p) * 1024 + d0];
        uint4 vb = *(const uint4*)&vh[(size_t)(s0 + 2 * p + 1) * 1024 + d0];
        const unsigned short* pa = (const unsigned short*)&va;
        const unsigned short* pb = (const unsigned short*)&vb;
        #pragma unroll
        for (int jj = 0; jj < 8; jj++)
          *(unsigned*)&Vt[(d0 + jj) * 72 + 2 * p] =
              (unsigned)pa[jj] | ((unsigned)pb[jj] << 16);
      }
    }

    f32x4 sacc[4];
    #pragma unroll
    for (int st = 0; st < 4; st++) sacc[st] = vzero;
    #pragma unroll
    for (int st = 0; st < 4; st++)
      #pragma unroll
      for (int kt = 0; kt < 2; kt++)
        sacc[st] = __builtin_amdgcn_mfma_f32_16x16x32_bf16(qf[kt], kf[st][kt], sacc[st], 0, 0, 0);

    float sv[4][4];
    #pragma unroll
    for (int st = 0; st < 4; st++)
      #pragma unroll
      for (int r = 0; r < 4; r++) {
        float x = sacc[st][r] * 0.125f;
        if (tt == tmax) {
          const int qi = qw + quad * 4 + r;
          const int si = s0 + st * 16 + l16;
          if (si > qi) x = -1e30f;
        }
        sv[st][r] = x;
      }

    float alpha[4];
    #pragma unroll
    for (int r = 0; r < 4; r++) {
      float rm = fmaxf(fmaxf(sv[0][r], sv[1][r]), fmaxf(sv[2][r], sv[3][r]));
      rm = fmaxf(rm, __shfl_xor(rm, 1, 64));
      rm = fmaxf(rm, __shfl_xor(rm, 2, 64));
      rm = fmaxf(rm, __shfl_xor(rm, 4, 64));
      rm = fmaxf(rm, __shfl_xor(rm, 8, 64));
      const float mn = fmaxf(mrun[r], rm);
      alpha[r] = __expf(mrun[r] - mn);
      mrun[r] = mn;
    }

    float psum[4] = {};
    #pragma unroll
    for (int st = 0; st < 4; st++)
      #pragma unroll
      for (int r = 0; r < 4; r++) {
        const float p_ = __expf(sv[st][r] - mrun[r]);
        psum[r] += p_;
        Pw[(quad * 4 + r) * 72 + st * 16 + l16] = f2bf(p_);
      }
    #pragma unroll
    for (int r = 0; r < 4; r++) {
      float ps = psum[r];
      ps += __shfl_xor(ps, 1, 64);
      ps += __shfl_xor(ps, 2, 64);
      ps += __shfl_xor(ps, 4, 64);
      ps += __shfl_xor(ps, 8, 64);
      lrun[r] = lrun[r] * alpha[r] + ps;
    }
    #pragma unroll
    for (int jt = 0; jt < 4; jt++)
      #pragma unroll
      for (int r = 0; r < 4; r++) oacc[jt][r] *= alpha[r];

    __syncthreads();                       // P/Vt visible to frag reads
    short8 pf[2], vf[4][2];
    #pragma unroll
    for (int kt = 0; kt < 2; kt++)
      pf[kt] = *(const short8*)&Pw[l16 * 72 + kt * 32 + quad * 8];
    #pragma unroll
    for (int jt = 0; jt < 4; jt++)
      #pragma unroll
      for (int kt = 0; kt < 2; kt++)
        vf[jt][kt] = *(const short8*)&Vt[(jt * 16 + l16) * 72 + kt * 32 + quad * 8];
    #pragma unroll
    for (int jt = 0; jt < 4; jt++)
      #pragma unroll
      for (int kt = 0; kt < 2; kt++)
        oacc[jt] = __builtin_amdgcn_mfma_f32_16x16x32_bf16(pf[kt], vf[jt][kt], oacc[jt], 0, 0, 0);
  }

  #pragma unroll
  for (int r = 0; r < 4; r++) {
    const float inv = 1.0f / lrun[r];
    const int qrow = qw + quad * 4 + r;
    #pragma unroll
    for (int jt = 0; jt < 4; jt++)
      oh[(size_t)qrow * 1024 + jt * 16 + l16] = f2bf(oacc[jt][r] * inv);
  }
}

// ---------------------------------------------------------------------------
extern "C" void kernel_launch(void* const* d_in, const int* in_sizes, int n_in,
                              void* d_out, int out_size, void* d_ws, size_t ws_size,
                              hipStream_t stream) {
  const int*   ids   = (const int*)d_in[0];
  const float* sig   = (const float*)d_in[1];
  const float* temb  = (const float*)d_in[2];
  const float* ropec = (const float*)d_in[3];
  const float* ropes = (const float*)d_in[4];
  const float* Wq = (const float*)d_in[5],  *bq = (const float*)d_in[6];
  const float* Wk = (const float*)d_in[7],  *bk = (const float*)d_in[8];
  const float* Wv = (const float*)d_in[9],  *bv = (const float*)d_in[10];
  const float* Wo = (const float*)d_in[11], *bo = (const float*)d_in[12];
  const float* ln1g = (const float*)d_in[13], *ln1b = (const float*)d_in[14];
  const float* ln2g = (const float*)d_in[15], *ln2b = (const float*)d_in[16];
  const float* W1 = (const float*)d_in[17], *b1 = (const float*)d_in[18];
  const float* W2 = (const float*)d_in[19], *b2 = (const float*)d_in[20];
  const float* agW1 = (const float*)d_in[21], *agb1 = (const float*)d_in[22];
  const float* agW2 = (const float*)d_in[23], *agb2 = (const float*)d_in[24];
  const float* fgW1 = (const float*)d_in[25], *fgb1 = (const float*)d_in[26];
  const float* fgW2 = (const float*)d_in[27], *fgb2 = (const float*)d_in[28];
  const float* lnfg = (const float*)d_in[29], *lnfb = (const float*)d_in[30];
  const float* Wout = (const float*)d_in[31], *bout = (const float*)d_in[32];

  const size_t DD = 1024 * 1024;
  uintptr_t w = (uintptr_t)d_ws;
  auto take = [&](size_t bytes) -> uintptr_t {
    uintptr_t p = w; w += (bytes + 255) & ~(size_t)255; return p;
  };
  unsigned short* wt_qkv = (unsigned short*)take((size_t)6 * 3 * DD * 2);   // [l][z][n][k]
  unsigned short* wt_o   = (unsigned short*)take((size_t)6 * DD * 2);
  unsigned short* wt_1   = (unsigned short*)take((size_t)6 * 4096 * 1024 * 2); // [l][n=F][k=D]
  unsigned short* wt_2   = (unsigned short*)take((size_t)6 * 1024 * 4096 * 2); // [l][n=D][k=F]
  unsigned short* wt_out = (unsigned short*)take((size_t)32000 * 1024 * 2);    // [v][k=D]
  float*          xbuf   = (float*)take((size_t)2048 * 1024 * 4);
  unsigned short* nbuf   = (unsigned short*)take((size_t)2048 * 1024 * 2);
  unsigned short* qbuf   = (unsigned short*)take((size_t)3 * 2048 * 1024 * 2);
  unsigned short* kbuf   = qbuf + (size_t)2048 * 1024;
  unsigned short* vbuf   = kbuf + (size_t)2048 * 1024;
  unsigned short* aobuf  = (unsigned short*)take((size_t)2048 * 1024 * 2);
  unsigned short* hbuf   = (unsigned short*)take((size_t)2048 * 4096 * 2);
  float*          gbuf   = (float*)take((size_t)2 * 6 * 2 * 1024 * 4);

  // ---- weights -> bf16 [N][K] ----
  transpose_k<<<dim3(32, 32, 6),  256, 0, stream>>>(Wq, wt_qkv + 0 * DD, 1024, 1024, DD, 3 * DD);
  transpose_k<<<dim3(32, 32, 6),  256, 0, stream>>>(Wk, wt_qkv + 1 * DD, 1024, 1024, DD, 3 * DD);
  transpose_k<<<dim3(32, 32, 6),  256, 0, stream>>>(Wv, wt_qkv + 2 * DD, 1024, 1024, DD, 3 * DD);
  transpose_k<<<dim3(32, 32, 6),  256, 0, stream>>>(Wo, wt_o, 1024, 1024, DD, DD);
  transpose_k<<<dim3(128, 32, 6), 256, 0, stream>>>(W1, wt_1, 1024, 4096, (size_t)4096 * 1024, (size_t)4096 * 1024);
  transpose_k<<<dim3(32, 128, 6), 256, 0, stream>>>(W2, wt_2, 4096, 1024, (size_t)4096 * 1024, (size_t)4096 * 1024);
  transpose_k<<<dim3(1000, 32, 1), 256, 0, stream>>>(Wout, wt_out, 1024, 32000, 0, 0);

  gates_k<<<dim3(2, 6, 2), 256, 0, stream>>>(sig, agW1, agb1, agW2, agb2, fgW1, fgb1, fgW2, fgb2, gbuf);
  embed_k<<<dim3(2048), 256, 0, stream>>>(ids, temb, xbuf);

  for (int l = 0; l < 6; l++) {
    ln_k<<<2048, 256, 0, stream>>>(xbuf, ln1g + l * 1024, ln1b + l * 1024, nbuf);

    GArgs a{};
    a.A = nbuf;
    a.Bt0 = wt_qkv + (size_t)(l * 3 + 0) * DD;
    a.Bt1 = wt_qkv + (size_t)(l * 3 + 1) * DD;
    a.Bt2 = wt_qkv + (size_t)(l * 3 + 2) * DD;
    a.bias0 = bq + l * 1024; a.bias1 = bk + l * 1024; a.bias2 = bv + l * 1024;
    a.ob0 = qbuf; a.ob1 = kbuf; a.ob2 = vbuf;
    a.ropec = ropec; a.ropes = ropes;
    a.M = 2048; a.N = 1024; a.K = 1024; a.epi = 1;
    gemm_bt<4><<<dim3(8, 16, 3), 256, 0, stream>>>(a);

    attn_k<<<dim3(32, 32), 128, 0, stream>>>(qbuf, kbuf, vbuf, aobuf);

    GArgs c{};
    c.A = aobuf; c.Bt0 = wt_o + (size_t)l * DD; c.bias0 = bo + l * 1024;
    c.xio = xbuf; c.gate = gbuf + (size_t)l * 2 * 1024;
    c.M = 2048; c.N = 1024; c.K = 1024; c.epi = 2;
    gemm_bt<2><<<dim3(8, 32, 1), 256, 0, stream>>>(c);

    ln_k<<<2048, 256, 0, stream>>>(xbuf, ln2g + l * 1024, ln2b + l * 1024, nbuf);

    GArgs f1{};
    f1.A = nbuf; f1.Bt0 = wt_1 + (size_t)l * 4096 * 1024; f1.bias0 = b1 + l * 4096;
    f1.ob0 = hbuf; f1.M = 2048; f1.N = 4096; f1.K = 1024; f1.epi = 3;
    gemm_bt<4><<<dim3(32, 16, 1), 256, 0, stream>>>(f1);

    GArgs f2{};
    f2.A = hbuf; f2.Bt0 = wt_2 + (size_t)l * 1024 * 4096; f2.bias0 = b2 + l * 1024;
    f2.xio = xbuf; f2.gate = gbuf + (size_t)(6 + l) * 2 * 1024;
    f2.M = 2048; f2.N = 1024; f2.K = 4096; f2.epi = 2;
    gemm_bt<2><<<dim3(8, 32, 1), 256, 0, stream>>>(f2);
  }

  ln_k<<<2048, 256, 0, stream>>>(xbuf, lnfg, lnfb, nbuf);

  GArgs lo{};
  lo.A = nbuf; lo.Bt0 = wt_out; lo.bias0 = bout;
  lo.xio = (float*)d_out;
  lo.M = 2048; lo.N = 32000; lo.K = 1024; lo.epi = 5;
  gemm_bt<4><<<dim3(250, 16, 1), 256, 0, stream>>>(lo);
}

// Round 4
// 2219.680 us; speedup vs baseline: 1.0175x; 1.0175x over previous
//
#include <hip/hip_runtime.h>

// ---------------------------------------------------------------------------
// TransformerLM forward on gfx950.
// L=6, D=1024, H=16, HD=64, F=4096, V=32000, S=1024, B=2, Mtok = B*S = 2048.
// Strategy: f32 weights pre-transposed to bf16 [N][K] in ws once per call;
// all matmuls via v_mfma_f32_16x16x32_bf16; residual stream in f32.
// R1: gemm_bt staging via global_load_lds (16B) with linear LDS + XOR-swizzled
//     source/read (T2 both-sides rule).  [verified: conflicts=0, 2235 us]
// R2: (a) bijective XCD-chunked block remap, m-fastest (T1)
//         [verified: logits FETCH 536->185 MB; dur neutral -> not BW-bound]
//     (b) attn_k 2 waves/block sharing one 32-row q-tile.
// R3: 2-phase pipelined K-loop (T3-min): LDS double-buffer, issue next tile's
//     global_load_lds BEFORE compute of current tile, ONE barrier per K-step.
//     Load latency now overlaps MFMA instead of sitting on the critical path
//     (grids are 1-2 blocks/CU -> no TLP cover; ILP must do it).
// ---------------------------------------------------------------------------

typedef __attribute__((ext_vector_type(8))) short short8;   // 8 bf16 = 4 VGPRs
typedef __attribute__((ext_vector_type(4))) float f32x4;

__device__ inline unsigned short f2bf(float f) {
  unsigned u = __builtin_bit_cast(unsigned, f);
  u += 0x7fffu + ((u >> 16) & 1u);           // RNE
  return (unsigned short)(u >> 16);
}

// global -> LDS direct copy, 16B per lane. LDS dest is wave-uniform base +
// lane*16 (linear); global src is per-lane (pre-swizzled by caller).
__device__ inline void gload_lds16(const unsigned short* g, unsigned short* l) {
  __builtin_amdgcn_global_load_lds(
      (const __attribute__((address_space(1))) void*)g,
      (__attribute__((address_space(3))) void*)l, 16, 0, 0);
}

// ---------------------------------------------------------------------------
// Transpose f32 [K][N] -> bf16 [N][K]
// ---------------------------------------------------------------------------
__global__ __launch_bounds__(256) void transpose_k(
    const float* __restrict__ src, unsigned short* __restrict__ dst,
    int K, int N, size_t srcStride, size_t dstStride) {
  __shared__ __align__(16) float tile[32 * 33];
  src += (size_t)blockIdx.z * srcStride;
  dst += (size_t)blockIdx.z * dstStride;
  const int k0 = blockIdx.y * 32, n0 = blockIdx.x * 32;
  const int t = threadIdx.x;
  {
    int k = t >> 3, n4 = (t & 7) << 2;
    float4 v = *(const float4*)&src[(size_t)(k0 + k) * N + n0 + n4];
    tile[k * 33 + n4 + 0] = v.x; tile[k * 33 + n4 + 1] = v.y;
    tile[k * 33 + n4 + 2] = v.z; tile[k * 33 + n4 + 3] = v.w;
  }
  __syncthreads();
  {
    int n = t >> 3, k4 = (t & 7) << 2;
    ushort4 o;
    o.x = f2bf(tile[(k4 + 0) * 33 + n]);
    o.y = f2bf(tile[(k4 + 1) * 33 + n]);
    o.z = f2bf(tile[(k4 + 2) * 33 + n]);
    o.w = f2bf(tile[(k4 + 3) * 33 + n]);
    *(ushort4*)&dst[(size_t)(n0 + n) * K + k0 + k4] = o;
  }
}

// ---------------------------------------------------------------------------
// Embedding gather: x[m][d] = emb[ids[m]][d]   (f32)
// ---------------------------------------------------------------------------
__global__ __launch_bounds__(256) void embed_k(
    const int* __restrict__ ids, const float* __restrict__ emb,
    float* __restrict__ x) {
  const int m = blockIdx.x, t = threadIdx.x;
  const int id = ids[m];
  ((float4*)(x + (size_t)m * 1024))[t] = ((const float4*)(emb + (size_t)id * 1024))[t];
}

// ---------------------------------------------------------------------------
// Tiny gate MLPs: sigmoid(gelu(sig@W1+b1)@W2+b2) for ag/fg, all layers/batch.
// gout layout: [w(ag=0,fg=1)][l][b][1024]
// ---------------------------------------------------------------------------
__global__ __launch_bounds__(256) void gates_k(
    const float* __restrict__ sig,
    const float* __restrict__ aW1, const float* __restrict__ ab1,
    const float* __restrict__ aW2, const float* __restrict__ ab2,
    const float* __restrict__ fW1, const float* __restrict__ fb1,
    const float* __restrict__ fW2, const float* __restrict__ fb2,
    float* __restrict__ gout) {
  const int b = blockIdx.x, l = blockIdx.y, w = blockIdx.z;
  const float* W1 = (w ? fW1 : aW1) + l * 96;
  const float* B1 = (w ? fb1 : ab1) + l * 32;
  const float* W2 = (w ? fW2 : aW2) + (size_t)l * 32 * 1024;
  const float* B2 = (w ? fb2 : ab2) + l * 1024;
  __shared__ float h[32];
  const int t = threadIdx.x;
  if (t < 32) {
    float a = sig[b * 3] * W1[t] + sig[b * 3 + 1] * W1[32 + t] + sig[b * 3 + 2] * W1[64 + t] + B1[t];
    h[t] = 0.5f * a * (1.0f + erff(a * 0.70710678118654752f));
  }
  __syncthreads();
  #pragma unroll
  for (int i = 0; i < 4; i++) {
    int d = t + i * 256;
    float a = B2[d];
    #pragma unroll
    for (int j = 0; j < 32; j++) a += h[j] * W2[j * 1024 + d];
    gout[(((size_t)w * 6 + l) * 2 + b) * 1024 + d] = 1.0f / (1.0f + expf(-a));
  }
}

// ---------------------------------------------------------------------------
// LayerNorm row kernel: x f32 [rows][1024] -> bf16 out (g,b applied)
// ---------------------------------------------------------------------------
__global__ __launch_bounds__(256) void ln_k(
    const float* __restrict__ x, const float* __restrict__ gw,
    const float* __restrict__ bw, unsigned short* __restrict__ out) {
  const int row = blockIdx.x, t = threadIdx.x;
  const float4 v = ((const float4*)(x + (size_t)row * 1024))[t];
  float s  = v.x + v.y + v.z + v.w;
  float s2 = v.x * v.x + v.y * v.y + v.z * v.z + v.w * v.w;
  #pragma unroll
  for (int m_ = 1; m_ < 64; m_ <<= 1) {
    s  += __shfl_xor(s, m_, 64);
    s2 += __shfl_xor(s2, m_, 64);
  }
  __shared__ float red[8];
  const int wv = t >> 6;
  if ((t & 63) == 0) { red[wv] = s; red[4 + wv] = s2; }
  __syncthreads();
  s  = red[0] + red[1] + red[2] + red[3];
  s2 = red[4] + red[5] + red[6] + red[7];
  const float mean = s * (1.0f / 1024.0f);
  const float var  = s2 * (1.0f / 1024.0f) - mean * mean;
  const float rstd = rsqrtf(var + 1e-5f);
  const float4 gv = ((const float4*)gw)[t];
  const float4 bv = ((const float4*)bw)[t];
  ushort4 o;
  o.x = f2bf((v.x - mean) * rstd * gv.x + bv.x);
  o.y = f2bf((v.y - mean) * rstd * gv.y + bv.y);
  o.z = f2bf((v.z - mean) * rstd * gv.z + bv.z);
  o.w = f2bf((v.w - mean) * rstd * gv.w + bv.w);
  ((ushort4*)(out + (size_t)row * 1024))[t] = o;
}

// ---------------------------------------------------------------------------
// Generic GEMM: C[M][N] = A[M][K](bf16) @ Bt[N][K](bf16)^T  + epilogue
// epi: 0 plain->bf16, 1 qkv (z<2 rope ->bf16, z==2 plain), 2 gate*val + resid
//      3 gelu->bf16, 5 logits->f32
//
// LDS layout (linear rows, 64 bf16 = 128 B per row), XOR-swizzled:
//   element (row, k) at byte  row*128 + (((k>>3) ^ (row&7)) * 16) + (k&7)*2
// Staged via global_load_lds: LDS dest linear (base + lane*16); the SOURCE
// column is pre-swizzled per lane:  col16 = (lane&7) ^ (lane>>3).
//
// K-loop is a 2-phase pipeline (R3): double-buffered LDS; next tile's
// global_load_lds issued BEFORE current tile's ds_read+MFMA; single
// __syncthreads per K-step (its vmcnt/lgkmcnt drain covers both hazards).
// ---------------------------------------------------------------------------
struct GArgs {
  const unsigned short *A, *Bt0, *Bt1, *Bt2;
  const float *bias0, *bias1, *bias2;
  unsigned short *ob0, *ob1, *ob2;
  float* xio;
  const float *gate, *ropec, *ropes;
  int M, N, K, epi;
};

template <int MT>   // rows per block = MT*32 (MT=4 ->128, MT=2 ->64); cols = 128
__global__ __launch_bounds__(256) void gemm_bt(GArgs g) {
  constexpr int BM = MT * 32;
  __shared__ __align__(16) unsigned short As[2][BM * 64];
  __shared__ __align__(16) unsigned short Bs[2][128 * 64];
  const int z = blockIdx.z;
  const unsigned short* A  = g.A;
  const unsigned short* Bt = (z == 0) ? g.Bt0 : (z == 1 ? g.Bt1 : g.Bt2);
  unsigned short* obf      = (z == 0) ? g.ob0 : (z == 1 ? g.ob1 : g.ob2);
  const float* bias        = (z == 0) ? g.bias0 : (z == 1 ? g.bias1 : g.bias2);

  // ---- XCD-aware bijective remap (per z-slice; m-fastest for B-panel reuse)
  const int nwg  = gridDim.x * gridDim.y;
  const int hwid = blockIdx.y * gridDim.x + blockIdx.x;
  const int xcd = hwid & 7, j8 = hwid >> 3;
  const int q8 = nwg >> 3, r8 = nwg & 7;
  const int logical =
      (xcd < r8 ? xcd * (q8 + 1) : r8 * (q8 + 1) + (xcd - r8) * q8) + j8;
  const int mIdx = logical % gridDim.y;
  const int nIdx = logical / gridDim.y;
  const int m0 = mIdx * BM, n0 = nIdx * 128;

  const int t = threadIdx.x;
  const int wave = t >> 6, lane = t & 63, l16 = lane & 15, quad = lane >> 4;
  const int wm = wave >> 1, wn = wave & 1;
  const int K_ = g.K;

  // staging constants: each global_load_lds covers 8 rows x 64 bf16 (1 KiB).
  const int srow = lane >> 3;                 // row within 8-row group
  const int scol = (lane & 7) ^ srow;         // pre-swizzled source col16

  const f32x4 vzero = {0.0f, 0.0f, 0.0f, 0.0f};
  f32x4 acc[MT][4];
  #pragma unroll
  for (int i = 0; i < MT; i++)
    #pragma unroll
    for (int j = 0; j < 4; j++) acc[i][j] = vzero;

  auto stage = [&](int buf, int k0) {
    #pragma unroll
    for (int i = 0; i < MT; i++) {            // stage A: BM x 64 bf16
      const int r0 = (wave * MT + i) * 8;
      gload_lds16(&A[(size_t)(m0 + r0 + srow) * K_ + k0 + scol * 8],
                  &As[buf][r0 * 64]);
    }
    #pragma unroll
    for (int i = 0; i < 4; i++) {             // stage B: 128 x 64 bf16
      const int r0 = (wave * 4 + i) * 8;
      gload_lds16(&Bt[(size_t)(n0 + r0 + srow) * K_ + k0 + scol * 8],
                  &Bs[buf][r0 * 64]);
    }
  };

  const int nk = K_ >> 6;                     // K-steps of 64
  stage(0, 0);
  __syncthreads();                            // drain prologue loads

  for (int kt = 0; kt < nk; kt++) {
    const int cur = kt & 1;
    if (kt + 1 < nk) stage(cur ^ 1, (kt + 1) << 6);   // issue next FIRST
    #pragma unroll
    for (int kk = 0; kk < 2; kk++) {
      short8 af[MT], bfr[4];
      #pragma unroll
      for (int mt = 0; mt < MT; mt++) {
        const int ar = wm * (MT * 16) + mt * 16 + l16;
        af[mt] = *(const short8*)&As[cur][ar * 64 + (((kk * 4 + quad) ^ (ar & 7)) << 3)];
      }
      #pragma unroll
      for (int nt = 0; nt < 4; nt++) {
        const int br = wn * 64 + nt * 16 + l16;
        bfr[nt] = *(const short8*)&Bs[cur][br * 64 + (((kk * 4 + quad) ^ (br & 7)) << 3)];
      }
      #pragma unroll
      for (int mt = 0; mt < MT; mt++)
        #pragma unroll
        for (int nt = 0; nt < 4; nt++)
          acc[mt][nt] = __builtin_amdgcn_mfma_f32_16x16x32_bf16(af[mt], bfr[nt], acc[mt][nt], 0, 0, 0);
    }
    __syncthreads();   // vmcnt: next tile landed; lgkmcnt: cur reads done
  }

  // epilogue: element (m, n): m = mbase + mt*16 + r, n = nb + nt*16
  const int mbase = m0 + wm * (MT * 16) + quad * 4;
  const int nb = n0 + wn * 64 + l16;
  const size_t Nsz = (size_t)g.N;
  float bv4[4];
  #pragma unroll
  for (int nt = 0; nt < 4; nt++) bv4[nt] = bias[nb + nt * 16];

  if (g.epi == 1 && z < 2) {           // RoPE for q/k, heads are 64-wide
    #pragma unroll
    for (int mt = 0; mt < MT; mt++) {
      float vv[4][4];
      #pragma unroll
      for (int nt = 0; nt < 4; nt++)
        #pragma unroll
        for (int r = 0; r < 4; r++) vv[nt][r] = acc[mt][nt][r] + bv4[nt];
      #pragma unroll
      for (int nt = 0; nt < 4; nt++) {
        const int d = (nb + nt * 16) & 63;
        #pragma unroll
        for (int r = 0; r < 4; r++) {
          const int m = mbase + mt * 16 + r;
          const int s = m & 1023;
          const float c = g.ropec[s * 64 + d], sn = g.ropes[s * 64 + d];
          const float rot = (nt < 2) ? -vv[nt + 2][r] : vv[nt - 2][r];
          obf[(size_t)m * Nsz + nb + nt * 16] = f2bf(vv[nt][r] * c + rot * sn);
        }
      }
    }
  } else if (g.epi <= 1) {             // plain bf16 (+bias)
    #pragma unroll
    for (int mt = 0; mt < MT; mt++)
      #pragma unroll
      for (int nt = 0; nt < 4; nt++)
        #pragma unroll
        for (int r = 0; r < 4; r++)
          obf[(size_t)(mbase + mt * 16 + r) * Nsz + nb + nt * 16] = f2bf(acc[mt][nt][r] + bv4[nt]);
  } else if (g.epi == 2) {             // (v+bias)*gate added into residual f32
    const int bb = m0 >> 10;           // batch uniform per block (128 | 1024)
    float gt[4];
    #pragma unroll
    for (int nt = 0; nt < 4; nt++) gt[nt] = g.gate[bb * 1024 + nb + nt * 16];
    #pragma unroll
    for (int mt = 0; mt < MT; mt++)
      #pragma unroll
      for (int nt = 0; nt < 4; nt++)
        #pragma unroll
        for (int r = 0; r < 4; r++) {
          const size_t idx = (size_t)(mbase + mt * 16 + r) * Nsz + nb + nt * 16;
          g.xio[idx] += (acc[mt][nt][r] + bv4[nt]) * gt[nt];
        }
  } else if (g.epi == 3) {             // exact gelu -> bf16
    #pragma unroll
    for (int mt = 0; mt < MT; mt++)
      #pragma unroll
      for (int nt = 0; nt < 4; nt++)
        #pragma unroll
        for (int r = 0; r < 4; r++) {
          float vg = acc[mt][nt][r] + bv4[nt];
          vg = 0.5f * vg * (1.0f + erff(vg * 0.70710678118654752f));
          obf[(size_t)(mbase + mt * 16 + r) * Nsz + nb + nt * 16] = f2bf(vg);
        }
  } else {                             // 5: logits f32
    #pragma unroll
    for (int mt = 0; mt < MT; mt++)
      #pragma unroll
      for (int nt = 0; nt < 4; nt++)
        #pragma unroll
        for (int r = 0; r < 4; r++)
          g.xio[(size_t)(mbase + mt * 16 + r) * Nsz + nb + nt * 16] = acc[mt][nt][r] + bv4[nt];
  }
}

// ---------------------------------------------------------------------------
// Flash attention, causal. 2 waves/block, one 32-row q-tile split 16+16
// (wave w owns rows q0+16w .. q0+16w+15); both waves have identical KV trip
// count since q0 % 32 == 0. Shared Vt staging (128 threads); per-wave Pl.
// q,k,v,o: bf16 [B*S][1024] with head offset h*64. Grid (S/32, B*H).
// ---------------------------------------------------------------------------
__global__ __launch_bounds__(128) void attn_k(
    const unsigned short* __restrict__ q, const unsigned short* __restrict__ k,
    const unsigned short* __restrict__ v, unsigned short* __restrict__ o) {
  __shared__ __align__(16) unsigned short Pl[2 * 16 * 72];
  __shared__ __align__(16) unsigned short Vt[64 * 72];
  const int t = threadIdx.x;
  const int wave = t >> 6, lane = t & 63, l16 = lane & 15, quad = lane >> 4;
  const int bh = blockIdx.y, b = bh >> 4, h = bh & 15;
  const int q0 = blockIdx.x * 32;
  const int qw = q0 + wave * 16;             // this wave's 16 q-rows
  const size_t base = (size_t)b * 1024 * 1024 + h * 64;
  const unsigned short* qh = q + base;
  const unsigned short* kh = k + base;
  const unsigned short* vh = v + base;
  unsigned short* oh = o + base;
  unsigned short* Pw = Pl + wave * 16 * 72;

  const f32x4 vzero = {0.0f, 0.0f, 0.0f, 0.0f};
  short8 qf[2];
  #pragma unroll
  for (int kt = 0; kt < 2; kt++)
    qf[kt] = *(const short8*)&qh[(size_t)(qw + l16) * 1024 + kt * 32 + quad * 8];

  f32x4 oacc[4];
  float mrun[4], lrun[4];
  #pragma unroll
  for (int jt = 0; jt < 4; jt++) oacc[jt] = vzero;
  #pragma unroll
  for (int r = 0; r < 4; r++) { mrun[r] = -1e30f; lrun[r] = 0.0f; }

  const int tmax = (q0 + 31) >> 6;
  for (int tt = 0; tt <= tmax; tt++) {
    const int s0 = tt * 64;
    short8 kf[4][2];
    #pragma unroll
    for (int st = 0; st < 4; st++)
      #pragma unroll
      for (int kt = 0; kt < 2; kt++)
        kf[st][kt] = *(const short8*)&kh[(size_t)(s0 + st * 16 + l16) * 1024 + kt * 32 + quad * 8];

    __syncthreads();                       // protect LDS from previous iter
    {                                      // stage V transposed: Vt[d][s], 128 thr
      const int p = t & 31, c0 = t >> 5;   // row-pair p, col-group c0 in [0,4)
      #pragma unroll
      for (int i = 0; i < 2; i++) {
        const int d0 = (c0 + i * 4) * 8;
        uint4 va = *(const uint4*)&vh[(size_t)(s0 + 2 * p) * 1024 + d0];
        uint4 vb = *(const uint4*)&vh[(size_t)(s0 + 2 * p + 1) * 1024 + d0];
        const unsigned short* pa = (const unsigned short*)&va;
        const unsigned short* pb = (const unsigned short*)&vb;
        #pragma unroll
        for (int jj = 0; jj < 8; jj++)
          *(unsigned*)&Vt[(d0 + jj) * 72 + 2 * p] =
              (unsigned)pa[jj] | ((unsigned)pb[jj] << 16);
      }
    }

    f32x4 sacc[4];
    #pragma unroll
    for (int st = 0; st < 4; st++) sacc[st] = vzero;
    #pragma unroll
    for (int st = 0; st < 4; st++)
      #pragma unroll
      for (int kt = 0; kt < 2; kt++)
        sacc[st] = __builtin_amdgcn_mfma_f32_16x16x32_bf16(qf[kt], kf[st][kt], sacc[st], 0, 0, 0);

    float sv[4][4];
    #pragma unroll
    for (int st = 0; st < 4; st++)
      #pragma unroll
      for (int r = 0; r < 4; r++) {
        float x = sacc[st][r] * 0.125f;
        if (tt == tmax) {
          const int qi = qw + quad * 4 + r;
          const int si = s0 + st * 16 + l16;
          if (si > qi) x = -1e30f;
        }
        sv[st][r] = x;
      }

    float alpha[4];
    #pragma unroll
    for (int r = 0; r < 4; r++) {
      float rm = fmaxf(fmaxf(sv[0][r], sv[1][r]), fmaxf(sv[2][r], sv[3][r]));
      rm = fmaxf(rm, __shfl_xor(rm, 1, 64));
      rm = fmaxf(rm, __shfl_xor(rm, 2, 64));
      rm = fmaxf(rm, __shfl_xor(rm, 4, 64));
      rm = fmaxf(rm, __shfl_xor(rm, 8, 64));
      const float mn = fmaxf(mrun[r], rm);
      alpha[r] = __expf(mrun[r] - mn);
      mrun[r] = mn;
    }

    float psum[4] = {};
    #pragma unroll
    for (int st = 0; st < 4; st++)
      #pragma unroll
      for (int r = 0; r < 4; r++) {
        const float p_ = __expf(sv[st][r] - mrun[r]);
        psum[r] += p_;
        Pw[(quad * 4 + r) * 72 + st * 16 + l16] = f2bf(p_);
      }
    #pragma unroll
    for (int r = 0; r < 4; r++) {
      float ps = psum[r];
      ps += __shfl_xor(ps, 1, 64);
      ps += __shfl_xor(ps, 2, 64);
      ps += __shfl_xor(ps, 4, 64);
      ps += __shfl_xor(ps, 8, 64);
      lrun[r] = lrun[r] * alpha[r] + ps;
    }
    #pragma unroll
    for (int jt = 0; jt < 4; jt++)
      #pragma unroll
      for (int r = 0; r < 4; r++) oacc[jt][r] *= alpha[r];

    __syncthreads();                       // P/Vt visible to frag reads
    short8 pf[2], vf[4][2];
    #pragma unroll
    for (int kt = 0; kt < 2; kt++)
      pf[kt] = *(const short8*)&Pw[l16 * 72 + kt * 32 + quad * 8];
    #pragma unroll
    for (int jt = 0; jt < 4; jt++)
      #pragma unroll
      for (int kt = 0; kt < 2; kt++)
        vf[jt][kt] = *(const short8*)&Vt[(jt * 16 + l16) * 72 + kt * 32 + quad * 8];
    #pragma unroll
    for (int jt = 0; jt < 4; jt++)
      #pragma unroll
      for (int kt = 0; kt < 2; kt++)
        oacc[jt] = __builtin_amdgcn_mfma_f32_16x16x32_bf16(pf[kt], vf[jt][kt], oacc[jt], 0, 0, 0);
  }

  #pragma unroll
  for (int r = 0; r < 4; r++) {
    const float inv = 1.0f / lrun[r];
    const int qrow = qw + quad * 4 + r;
    #pragma unroll
    for (int jt = 0; jt < 4; jt++)
      oh[(size_t)qrow * 1024 + jt * 16 + l16] = f2bf(oacc[jt][r] * inv);
  }
}

// ---------------------------------------------------------------------------
extern "C" void kernel_launch(void* const* d_in, const int* in_sizes, int n_in,
                              void* d_out, int out_size, void* d_ws, size_t ws_size,
                              hipStream_t stream) {
  const int*   ids   = (const int*)d_in[0];
  const float* sig   = (const float*)d_in[1];
  const float* temb  = (const float*)d_in[2];
  const float* ropec = (const float*)d_in[3];
  const float* ropes = (const float*)d_in[4];
  const float* Wq = (const float*)d_in[5],  *bq = (const float*)d_in[6];
  const float* Wk = (const float*)d_in[7],  *bk = (const float*)d_in[8];
  const float* Wv = (const float*)d_in[9],  *bv = (const float*)d_in[10];
  const float* Wo = (const float*)d_in[11], *bo = (const float*)d_in[12];
  const float* ln1g = (const float*)d_in[13], *ln1b = (const float*)d_in[14];
  const float* ln2g = (const float*)d_in[15], *ln2b = (const float*)d_in[16];
  const float* W1 = (const float*)d_in[17], *b1 = (const float*)d_in[18];
  const float* W2 = (const float*)d_in[19], *b2 = (const float*)d_in[20];
  const float* agW1 = (const float*)d_in[21], *agb1 = (const float*)d_in[22];
  const float* agW2 = (const float*)d_in[23], *agb2 = (const float*)d_in[24];
  const float* fgW1 = (const float*)d_in[25], *fgb1 = (const float*)d_in[26];
  const float* fgW2 = (const float*)d_in[27], *fgb2 = (const float*)d_in[28];
  const float* lnfg = (const float*)d_in[29], *lnfb = (const float*)d_in[30];
  const float* Wout = (const float*)d_in[31], *bout = (const float*)d_in[32];

  const size_t DD = 1024 * 1024;
  uintptr_t w = (uintptr_t)d_ws;
  auto take = [&](size_t bytes) -> uintptr_t {
    uintptr_t p = w; w += (bytes + 255) & ~(size_t)255; return p;
  };
  unsigned short* wt_qkv = (unsigned short*)take((size_t)6 * 3 * DD * 2);   // [l][z][n][k]
  unsigned short* wt_o   = (unsigned short*)take((size_t)6 * DD * 2);
  unsigned short* wt_1   = (unsigned short*)take((size_t)6 * 4096 * 1024 * 2); // [l][n=F][k=D]
  unsigned short* wt_2   = (unsigned short*)take((size_t)6 * 1024 * 4096 * 2); // [l][n=D][k=F]
  unsigned short* wt_out = (unsigned short*)take((size_t)32000 * 1024 * 2);    // [v][k=D]
  float*          xbuf   = (float*)take((size_t)2048 * 1024 * 4);
  unsigned short* nbuf   = (unsigned short*)take((size_t)2048 * 1024 * 2);
  unsigned short* qbuf   = (unsigned short*)take((size_t)3 * 2048 * 1024 * 2);
  unsigned short* kbuf   = qbuf + (size_t)2048 * 1024;
  unsigned short* vbuf   = kbuf + (size_t)2048 * 1024;
  unsigned short* aobuf  = (unsigned short*)take((size_t)2048 * 1024 * 2);
  unsigned short* hbuf   = (unsigned short*)take((size_t)2048 * 4096 * 2);
  float*          gbuf   = (float*)take((size_t)2 * 6 * 2 * 1024 * 4);

  // ---- weights -> bf16 [N][K] ----
  transpose_k<<<dim3(32, 32, 6),  256, 0, stream>>>(Wq, wt_qkv + 0 * DD, 1024, 1024, DD, 3 * DD);
  transpose_k<<<dim3(32, 32, 6),  256, 0, stream>>>(Wk, wt_qkv + 1 * DD, 1024, 1024, DD, 3 * DD);
  transpose_k<<<dim3(32, 32, 6),  256, 0, stream>>>(Wv, wt_qkv + 2 * DD, 1024, 1024, DD, 3 * DD);
  transpose_k<<<dim3(32, 32, 6),  256, 0, stream>>>(Wo, wt_o, 1024, 1024, DD, DD);
  transpose_k<<<dim3(128, 32, 6), 256, 0, stream>>>(W1, wt_1, 1024, 4096, (size_t)4096 * 1024, (size_t)4096 * 1024);
  transpose_k<<<dim3(32, 128, 6), 256, 0, stream>>>(W2, wt_2, 4096, 1024, (size_t)4096 * 1024, (size_t)4096 * 1024);
  transpose_k<<<dim3(1000, 32, 1), 256, 0, stream>>>(Wout, wt_out, 1024, 32000, 0, 0);

  gates_k<<<dim3(2, 6, 2), 256, 0, stream>>>(sig, agW1, agb1, agW2, agb2, fgW1, fgb1, fgW2, fgb2, gbuf);
  embed_k<<<dim3(2048), 256, 0, stream>>>(ids, temb, xbuf);

  for (int l = 0; l < 6; l++) {
    ln_k<<<2048, 256, 0, stream>>>(xbuf, ln1g + l * 1024, ln1b + l * 1024, nbuf);

    GArgs a{};
    a.A = nbuf;
    a.Bt0 = wt_qkv + (size_t)(l * 3 + 0) * DD;
    a.Bt1 = wt_qkv + (size_t)(l * 3 + 1) * DD;
    a.Bt2 = wt_qkv + (size_t)(l * 3 + 2) * DD;
    a.bias0 = bq + l * 1024; a.bias1 = bk + l * 1024; a.bias2 = bv + l * 1024;
    a.ob0 = qbuf; a.ob1 = kbuf; a.ob2 = vbuf;
    a.ropec = ropec; a.ropes = ropes;
    a.M = 2048; a.N = 1024; a.K = 1024; a.epi = 1;
    gemm_bt<4><<<dim3(8, 16, 3), 256, 0, stream>>>(a);

    attn_k<<<dim3(32, 32), 128, 0, stream>>>(qbuf, kbuf, vbuf, aobuf);

    GArgs c{};
    c.A = aobuf; c.Bt0 = wt_o + (size_t)l * DD; c.bias0 = bo + l * 1024;
    c.xio = xbuf; c.gate = gbuf + (size_t)l * 2 * 1024;
    c.M = 2048; c.N = 1024; c.K = 1024; c.epi = 2;
    gemm_bt<2><<<dim3(8, 32, 1), 256, 0, stream>>>(c);

    ln_k<<<2048, 256, 0, stream>>>(xbuf, ln2g + l * 1024, ln2b + l * 1024, nbuf);

    GArgs f1{};
    f1.A = nbuf; f1.Bt0 = wt_1 + (size_t)l * 4096 * 1024; f1.bias0 = b1 + l * 4096;
    f1.ob0 = hbuf; f1.M = 2048; f1.N = 4096; f1.K = 1024; f1.epi = 3;
    gemm_bt<4><<<dim3(32, 16, 1), 256, 0, stream>>>(f1);

    GArgs f2{};
    f2.A = hbuf; f2.Bt0 = wt_2 + (size_t)l * 1024 * 4096; f2.bias0 = b2 + l * 1024;
    f2.xio = xbuf; f2.gate = gbuf + (size_t)(6 + l) * 2 * 1024;
    f2.M = 2048; f2.N = 1024; f2.K = 4096; f2.epi = 2;
    gemm_bt<2><<<dim3(8, 32, 1), 256, 0, stream>>>(f2);
  }

  ln_k<<<2048, 256, 0, stream>>>(xbuf, lnfg, lnfb, nbuf);

  GArgs lo{};
  lo.A = nbuf; lo.Bt0 = wt_out; lo.bias0 = bout;
  lo.xio = (float*)d_out;
  lo.M = 2048; lo.N = 32000; lo.K = 1024; lo.epi = 5;
  gemm_bt<4><<<dim3(250, 16, 1), 256, 0, stream>>>(lo);
}